// Round 13
// baseline (95.368 us; speedup 1.0000x reference)
//
#include <hip/hip_runtime.h>

typedef __attribute__((ext_vector_type(8))) short bf16x8;
typedef __attribute__((ext_vector_type(4))) float f32x4;
typedef __attribute__((ext_vector_type(4))) unsigned short u16x4;
typedef __attribute__((ext_vector_type(8))) unsigned short u16x8;
typedef __attribute__((ext_vector_type(4))) unsigned int u32x4;

#define MFMA(a, b, c) __builtin_amdgcn_mfma_f32_16x16x32_bf16(a, b, c, 0, 0, 0)

static __device__ __forceinline__ unsigned short f2bf(float x) {
    union { float f; unsigned u; } v; v.f = x;
    unsigned r = v.u + 0x7fffu + ((v.u >> 16) & 1u);   // round-to-nearest-even
    return (unsigned short)(r >> 16);
}

// P-fragment pack (verified rounds 4-12).
static __device__ __forceinline__ bf16x8 pack_pa(
    float ea0, float ea1, float ea2, float ea3,
    float eb0, float eb1, float eb2, float eb3, bool odd)
{
    unsigned a1, a2, b1, b2;
    asm("v_cvt_pk_bf16_f32 %0, %1, %2" : "=v"(a1) : "v"(ea0), "v"(ea1));
    asm("v_cvt_pk_bf16_f32 %0, %1, %2" : "=v"(a2) : "v"(ea2), "v"(ea3));
    asm("v_cvt_pk_bf16_f32 %0, %1, %2" : "=v"(b1) : "v"(eb0), "v"(eb1));
    asm("v_cvt_pk_bf16_f32 %0, %1, %2" : "=v"(b2) : "v"(eb2), "v"(eb3));
    asm("v_permlane32_swap_b32 %0, %1" : "+v"(a1), "+v"(b1));
    asm("v_permlane32_swap_b32 %0, %1" : "+v"(a2), "+v"(b2));
    int sa1 = __shfl_xor((int)a1, 16);
    int sa2 = __shfl_xor((int)a2, 16);
    int sb1 = __shfl_xor((int)b1, 16);
    int sb2 = __shfl_xor((int)b2, 16);
    u32x4 paw;
    paw[0] = odd ? (unsigned)sb1 : a1;
    paw[1] = odd ? (unsigned)sb2 : a2;
    paw[2] = odd ? b1 : (unsigned)sa1;
    paw[3] = odd ? b2 : (unsigned)sa2;
    return __builtin_bit_cast(bf16x8, paw);
}

// ---------------- Kernel 0: W [1024][64] f32 -> Wt [3][64][1024] bf16 ----------------
__global__ __launch_bounds__(256) void wtrans_k(
    const float* __restrict__ Wk, const float* __restrict__ Wq,
    const float* __restrict__ Wv, unsigned short* __restrict__ Wt)
{
    __shared__ float tl[64][65];
    const int w = blockIdx.x >> 4, kt = blockIdx.x & 15;
    const float* W = (w == 0) ? Wk : (w == 1) ? Wq : Wv;
    const int tid = threadIdx.x;
#pragma unroll
    for (int rep = 0; rep < 4; rep++) {
        int flat = rep * 256 + tid;
        int rr = flat >> 4, c4 = (flat & 15) * 4;
        f32x4 v = *(const f32x4*)(W + (kt * 64 + rr) * 64 + c4);
#pragma unroll
        for (int jj = 0; jj < 4; jj++) tl[c4 + jj][rr] = v[jj];
    }
    __syncthreads();
#pragma unroll
    for (int rep = 0; rep < 2; rep++) {
        int flat = rep * 256 + tid;
        int n = flat >> 3, k8 = (flat & 7) * 8;
        u16x8 h;
#pragma unroll
        for (int jj = 0; jj < 8; jj++) h[jj] = f2bf(tl[n][k8 + jj]);
        *(u16x8*)(Wt + w * 65536 + n * 1024 + kt * 64 + k8) = h;
    }
}

// ---------------- Kernel 1: QKV v3 — DIAGNOSTIC x3 REPLICATION ----------------
// Body identical to round 12; rep loop surfaces this dispatch in rocprof top-5.
__global__ __launch_bounds__(256) void qkv_k(
    const float* __restrict__ x, const unsigned short* __restrict__ Wt,
    unsigned short* __restrict__ Qb, unsigned short* __restrict__ Kb,
    unsigned short* __restrict__ Vt)
{
    __shared__ __align__(16) unsigned short xl[2][32][72];
    __shared__ __align__(16) unsigned short wl[2][192][72];
    const int tid = threadIdx.x;
    const int wid = tid >> 6, lane = tid & 63;
    const int lrow = lane & 15, g = lane >> 4;
    const int mbase = blockIdx.x * 32;
    const int msrow = (wid & 1) * 16;
    const int ntbase = (wid >> 1) * 6;

    const int srow = tid >> 3, c8 = (tid & 7) * 8;

    f32x4 acc[6];

#pragma unroll 1
    for (int rep = 0; rep < 3; ++rep) {
#pragma unroll
        for (int j = 0; j < 6; j++) acc[j] = (f32x4){0.f, 0.f, 0.f, 0.f};

        f32x4 vx0, vx1;
        u16x8 rw0, rw1, rw2, rw3, rw4, rw5;
        {
            const float* xs = x + (mbase + srow) * 1024 + c8;
            vx0 = *(const f32x4*)(xs);
            vx1 = *(const f32x4*)(xs + 4);
            const unsigned short* ws = Wt + srow * 1024 + c8;
            rw0 = *(const u16x8*)(ws);
            rw1 = *(const u16x8*)(ws + 32 * 1024);
            rw2 = *(const u16x8*)(ws + 64 * 1024);
            rw3 = *(const u16x8*)(ws + 96 * 1024);
            rw4 = *(const u16x8*)(ws + 128 * 1024);
            rw5 = *(const u16x8*)(ws + 160 * 1024);
        }

#pragma unroll 1
        for (int t = 0; t < 16; ++t) {
            const int buf = t & 1;
            {
                unsigned d0, d1, d2, d3;
                asm("v_cvt_pk_bf16_f32 %0, %1, %2" : "=v"(d0) : "v"(vx0[0]), "v"(vx0[1]));
                asm("v_cvt_pk_bf16_f32 %0, %1, %2" : "=v"(d1) : "v"(vx0[2]), "v"(vx0[3]));
                asm("v_cvt_pk_bf16_f32 %0, %1, %2" : "=v"(d2) : "v"(vx1[0]), "v"(vx1[1]));
                asm("v_cvt_pk_bf16_f32 %0, %1, %2" : "=v"(d3) : "v"(vx1[2]), "v"(vx1[3]));
                u32x4 pk; pk[0] = d0; pk[1] = d1; pk[2] = d2; pk[3] = d3;
                *(u32x4*)&xl[buf][srow][c8] = pk;
                *(u16x8*)&wl[buf][srow][c8]        = rw0;
                *(u16x8*)&wl[buf][srow + 32][c8]   = rw1;
                *(u16x8*)&wl[buf][srow + 64][c8]   = rw2;
                *(u16x8*)&wl[buf][srow + 96][c8]   = rw3;
                *(u16x8*)&wl[buf][srow + 128][c8]  = rw4;
                *(u16x8*)&wl[buf][srow + 160][c8]  = rw5;
            }
            if (t < 15) {
                const int kc = (t + 1) * 64;
                const float* xs = x + (mbase + srow) * 1024 + kc + c8;
                vx0 = *(const f32x4*)(xs);
                vx1 = *(const f32x4*)(xs + 4);
                const unsigned short* ws = Wt + srow * 1024 + kc + c8;
                rw0 = *(const u16x8*)(ws);
                rw1 = *(const u16x8*)(ws + 32 * 1024);
                rw2 = *(const u16x8*)(ws + 64 * 1024);
                rw3 = *(const u16x8*)(ws + 96 * 1024);
                rw4 = *(const u16x8*)(ws + 128 * 1024);
                rw5 = *(const u16x8*)(ws + 160 * 1024);
            }
            __syncthreads();
#pragma unroll
            for (int ks = 0; ks < 2; ks++) {
                bf16x8 a = *(const bf16x8*)&xl[buf][msrow + lrow][ks * 32 + g * 8];
#pragma unroll
                for (int j = 0; j < 6; j++) {
                    bf16x8 b = *(const bf16x8*)&wl[buf][(ntbase + j) * 16 + lrow][ks * 32 + g * 8];
                    acc[j] = MFMA(a, b, acc[j]);
                }
            }
        }
        __syncthreads();                 // rep boundary: all buf reads done
    }

#pragma unroll
    for (int j = 0; j < 6; j++) {
        int nt = ntbase + j;
        int w = nt >> 2;
        int col = (nt & 3) * 16 + lrow;
        int r0 = mbase + msrow + g * 4;
        if (w == 2) {
            int b = r0 >> 11, tt = r0 & 2047;
            u16x4 pv;
            pv[0] = f2bf(acc[j][0]); pv[1] = f2bf(acc[j][1]);
            pv[2] = f2bf(acc[j][2]); pv[3] = f2bf(acc[j][3]);
            *(u16x4*)(Vt + b * 131072 + col * 2048 + tt) = pv;
        } else {
            unsigned short* dst = (w == 0) ? Kb : Qb;
#pragma unroll
            for (int i = 0; i < 4; i++)
                dst[(r0 + i) * 64 + col] = f2bf(acc[j][i]);
        }
    }
}

// ---------------- Kernel 2: attention v12 — DIAGNOSTIC x3 REPLICATION ----------------
__global__ __launch_bounds__(256) void attn_k(
    const unsigned short* __restrict__ Qb, const unsigned short* __restrict__ Kb,
    const unsigned short* __restrict__ Vt, float* __restrict__ pO,
    float* __restrict__ pL)
{
    __shared__ __align__(16) unsigned short klds[2][64][64];
    __shared__ __align__(16) unsigned short vlds[2][64][64];
    const int tid = threadIdx.x;
    const int w = tid >> 6, lane = tid & 63;
    const int lrow = lane & 15, g = lane >> 4;
    const int bid = blockIdx.x;
    const int bandIdx = bid >> 5;
    const int batch = (bid >> 2) & 7;
    const int j = bid & 3;
    const int B = (bandIdx < 16) ? (31 - bandIdx) : (bandIdx - 16);

    const int qb  = B * 64;
    const int nch = B + 1;
    const int nc  = (nch > j) ? ((nch - j + 3) >> 2) : 0;

    const unsigned short* Kbase = Kb + batch * 2048 * 64;
    const unsigned short* Vbase = Vt + batch * 131072;
    const float C2 = 0.03125f * 1.44269504088896f;      // E^-0.5 * log2(e)

    const int sr = tid >> 2;
    const int sc32 = tid & 3;
    const int sb0 = sr * 128 + (((sc32 * 2)     ^ (sr & 7)) << 4);
    const int sb1 = sr * 128 + (((sc32 * 2 + 1) ^ (sr & 7)) << 4);

    const int swz = (lrow & 7) << 4;
    const int rb0 = (lrow) * 128, rb1 = (16 + lrow) * 128,
              rb2 = (32 + lrow) * 128, rb3 = (48 + lrow) * 128;
    const int gk0 = (g << 4) ^ swz;
    const int gk1 = ((4 + g) << 4) ^ swz;
    const bool odd = (g & 1);

    const unsigned short* Qrow = Qb + (batch * 2048 + qb + w * 16 + lrow) * 64;
    bf16x8 q0 = *(const bf16x8*)(Qrow + g * 8);
    bf16x8 q1 = *(const bf16x8*)(Qrow + 32 + g * 8);
    const int qglob = qb + w * 16 + lrow;

#pragma unroll 1
    for (int rep = 0; rep < 3; ++rep) {
        f32x4 o0 = {0.f,0.f,0.f,0.f}, o1 = o0, o2 = o0, o3 = o0;
        float lsum = 0.f;

        u16x8 rk0 = {}, rk1 = {}, rv0 = {}, rv1 = {};
        if (nc > 0) {
            const int kvb = j * 64;
            const unsigned short* ksrc = Kbase + (kvb + sr) * 64 + sc32 * 16;
            rk0 = *(const u16x8*)(ksrc); rk1 = *(const u16x8*)(ksrc + 8);
            const unsigned short* vsrc = Vbase + sr * 2048 + kvb + sc32 * 16;
            rv0 = *(const u16x8*)(vsrc); rv1 = *(const u16x8*)(vsrc + 8);
            char* kb = (char*)&klds[0][0][0];
            char* vb = (char*)&vlds[0][0][0];
            *(u16x8*)(kb + sb0) = rk0; *(u16x8*)(kb + sb1) = rk1;
            *(u16x8*)(vb + sb0) = rv0; *(u16x8*)(vb + sb1) = rv1;
        }
        __syncthreads();

        for (int idx = 0; idx < nc; ++idx) {
            const int c = j + idx * 4;
            const int cur = idx & 1;
            const int kvbase = c * 64;
            if (idx + 1 < nc) {
                const int kvb = kvbase + 256;
                const unsigned short* ksrc = Kbase + (kvb + sr) * 64 + sc32 * 16;
                rk0 = *(const u16x8*)(ksrc); rk1 = *(const u16x8*)(ksrc + 8);
                const unsigned short* vsrc = Vbase + sr * 2048 + kvb + sc32 * 16;
                rv0 = *(const u16x8*)(vsrc); rv1 = *(const u16x8*)(vsrc + 8);
            }

            const char* kb = (const char*)&klds[cur][0][0];
            const char* vb = (const char*)&vlds[cur][0][0];

            f32x4 t0 = {0.f,0.f,0.f,0.f}, t1 = t0, t2 = t0, t3 = t0;
            {
                bf16x8 a;
                a = *(const bf16x8*)(kb + rb0 + gk0); t0 = MFMA(a, q0, t0);
                a = *(const bf16x8*)(kb + rb0 + gk1); t0 = MFMA(a, q1, t0);
                a = *(const bf16x8*)(kb + rb1 + gk0); t1 = MFMA(a, q0, t1);
                a = *(const bf16x8*)(kb + rb1 + gk1); t1 = MFMA(a, q1, t1);
                a = *(const bf16x8*)(kb + rb2 + gk0); t2 = MFMA(a, q0, t2);
                a = *(const bf16x8*)(kb + rb2 + gk1); t2 = MFMA(a, q1, t2);
                a = *(const bf16x8*)(kb + rb3 + gk0); t3 = MFMA(a, q0, t3);
                a = *(const bf16x8*)(kb + rb3 + gk1); t3 = MFMA(a, q1, t3);
            }

            const bool maskc = (c == nch - 1);
            float eA[4], eB[4], eC[4], eD[4];
#pragma unroll
            for (int u = 0; u < 4; u++) {
                float v0 = t0[u] * C2, v1 = t1[u] * C2,
                      v2 = t2[u] * C2, v3 = t3[u] * C2;
                if (maskc) {
                    int kvr = kvbase + g * 4 + u;
                    v0 = (kvr      > qglob) ? -INFINITY : v0;
                    v1 = (kvr + 16 > qglob) ? -INFINITY : v1;
                    v2 = (kvr + 32 > qglob) ? -INFINITY : v2;
                    v3 = (kvr + 48 > qglob) ? -INFINITY : v3;
                }
                eA[u] = __builtin_exp2f(v0);
                eB[u] = __builtin_exp2f(v1);
                eC[u] = __builtin_exp2f(v2);
                eD[u] = __builtin_exp2f(v3);
                lsum += (eA[u] + eB[u]) + (eC[u] + eD[u]);
            }

            bf16x8 pa0 = pack_pa(eA[0],eA[1],eA[2],eA[3], eB[0],eB[1],eB[2],eB[3], odd);
            bf16x8 pa1 = pack_pa(eC[0],eC[1],eC[2],eC[3], eD[0],eD[1],eD[2],eD[3], odd);

            {
                bf16x8 vv;
                vv = *(const bf16x8*)(vb + rb0 + gk0); o0 = MFMA(pa0, vv, o0);
                vv = *(const bf16x8*)(vb + rb0 + gk1); o0 = MFMA(pa1, vv, o0);
                vv = *(const bf16x8*)(vb + rb1 + gk0); o1 = MFMA(pa0, vv, o1);
                vv = *(const bf16x8*)(vb + rb1 + gk1); o1 = MFMA(pa1, vv, o1);
                vv = *(const bf16x8*)(vb + rb2 + gk0); o2 = MFMA(pa0, vv, o2);
                vv = *(const bf16x8*)(vb + rb2 + gk1); o2 = MFMA(pa1, vv, o2);
                vv = *(const bf16x8*)(vb + rb3 + gk0); o3 = MFMA(pa0, vv, o3);
                vv = *(const bf16x8*)(vb + rb3 + gk1); o3 = MFMA(pa1, vv, o3);
            }

            __syncthreads();
            if (idx + 1 < nc) {
                char* kw = (char*)&klds[cur ^ 1][0][0];
                char* vw = (char*)&vlds[cur ^ 1][0][0];
                *(u16x8*)(kw + sb0) = rk0; *(u16x8*)(kw + sb1) = rk1;
                *(u16x8*)(vw + sb0) = rv0; *(u16x8*)(vw + sb1) = rv1;
            }
            __syncthreads();
        }

        const int qrow0 = batch * 2048 + qb + w * 16;
        float* po = pO + ((size_t)j * 16384 + qrow0) * 64;
#pragma unroll
        for (int u = 0; u < 4; u++) {
            int r = (g * 4 + u) * 64;
            po[r +      lrow] = o0[u];
            po[r + 16 + lrow] = o1[u];
            po[r + 32 + lrow] = o2[u];
            po[r + 48 + lrow] = o3[u];
        }
        lsum += __shfl_xor(lsum, 16);
        lsum += __shfl_xor(lsum, 32);
        if (lane < 16) pL[j * 16384 + qrow0 + lane] = lsum;
        __syncthreads();                 // rep boundary
    }
}

// ---------------- Kernel 3: merge the four kv-quarter partials ----------------
__global__ __launch_bounds__(256) void comb_k(
    const float* __restrict__ pO, const float* __restrict__ pL,
    float* __restrict__ out)
{
    const int J = 16384 * 64;
    int id = blockIdx.x * 256 + threadIdx.x;
    int row = id >> 2, q = (id & 3) * 16;
    float inv = 1.f / (pL[row] + pL[16384 + row] + pL[32768 + row] + pL[49152 + row]);
    const float* p0 = pO + row * 64 + q;
    float* op = out + row * 64 + q;
#pragma unroll
    for (int k = 0; k < 4; k++) {
        f32x4 s = *(const f32x4*)(p0 + 4 * k)
                + *(const f32x4*)(p0 + J + 4 * k)
                + *(const f32x4*)(p0 + 2 * J + 4 * k)
                + *(const f32x4*)(p0 + 3 * J + 4 * k);
        *(f32x4*)(op + 4 * k) = s * inv;
    }
}

extern "C" void kernel_launch(void* const* d_in, const int* in_sizes, int n_in,
                              void* d_out, int out_size, void* d_ws, size_t ws_size,
                              hipStream_t stream) {
    const float* x  = (const float*)d_in[0];
    const float* Wk = (const float*)d_in[1];
    const float* Wq = (const float*)d_in[2];
    const float* Wv = (const float*)d_in[3];
    float* out = (float*)d_out;

    unsigned short* Wt = (unsigned short*)d_ws;        // [192][1024] bf16
    unsigned short* Kb = Wt + 3 * 65536;               // [16384][64]
    unsigned short* Qb = Kb + 16384 * 64;              // [16384][64]
    unsigned short* Vt = Qb + 16384 * 64;              // [8][64][2048]
    float* pO = (float*)(Vt + 131072 * 8);             // [4][16384][64] f32 partial o
    float* pL = pO + 4 * 16384 * 64;                   // [4][16384] f32 partial l

    wtrans_k<<<48, 256, 0, stream>>>(Wk, Wq, Wv, Wt);
    qkv_k<<<512, 256, 0, stream>>>(x, Wt, Qb, Kb, Vt);
    attn_k<<<1024, 256, 0, stream>>>(Qb, Kb, Vt, pO, pL);
    comb_k<<<256, 256, 0, stream>>>(pO, pL, out);
}

// Round 14
// 47.260 us; speedup vs baseline: 2.0180x; 2.0180x over previous
//
#include <hip/hip_runtime.h>

typedef __attribute__((ext_vector_type(8))) short bf16x8;
typedef __attribute__((ext_vector_type(4))) float f32x4;
typedef __attribute__((ext_vector_type(4))) unsigned short u16x4;
typedef __attribute__((ext_vector_type(8))) unsigned short u16x8;
typedef __attribute__((ext_vector_type(4))) unsigned int u32x4;

#define MFMA(a, b, c) __builtin_amdgcn_mfma_f32_16x16x32_bf16(a, b, c, 0, 0, 0)

static __device__ __forceinline__ unsigned short f2bf(float x) {
    union { float f; unsigned u; } v; v.f = x;
    unsigned r = v.u + 0x7fffu + ((v.u >> 16) & 1u);   // round-to-nearest-even
    return (unsigned short)(r >> 16);
}

// P-fragment pack (verified rounds 4-13).
static __device__ __forceinline__ bf16x8 pack_pa(
    float ea0, float ea1, float ea2, float ea3,
    float eb0, float eb1, float eb2, float eb3, bool odd)
{
    unsigned a1, a2, b1, b2;
    asm("v_cvt_pk_bf16_f32 %0, %1, %2" : "=v"(a1) : "v"(ea0), "v"(ea1));
    asm("v_cvt_pk_bf16_f32 %0, %1, %2" : "=v"(a2) : "v"(ea2), "v"(ea3));
    asm("v_cvt_pk_bf16_f32 %0, %1, %2" : "=v"(b1) : "v"(eb0), "v"(eb1));
    asm("v_cvt_pk_bf16_f32 %0, %1, %2" : "=v"(b2) : "v"(eb2), "v"(eb3));
    asm("v_permlane32_swap_b32 %0, %1" : "+v"(a1), "+v"(b1));
    asm("v_permlane32_swap_b32 %0, %1" : "+v"(a2), "+v"(b2));
    int sa1 = __shfl_xor((int)a1, 16);
    int sa2 = __shfl_xor((int)a2, 16);
    int sb1 = __shfl_xor((int)b1, 16);
    int sb2 = __shfl_xor((int)b2, 16);
    u32x4 paw;
    paw[0] = odd ? (unsigned)sb1 : a1;
    paw[1] = odd ? (unsigned)sb2 : a2;
    paw[2] = odd ? b1 : (unsigned)sa1;
    paw[3] = odd ? b2 : (unsigned)sa2;
    return __builtin_bit_cast(bf16x8, paw);
}

// ---------------- Kernel 0: W [1024][64] f32 -> Wt [3][64][1024] bf16 ----------------
__global__ __launch_bounds__(256) void wtrans_k(
    const float* __restrict__ Wk, const float* __restrict__ Wq,
    const float* __restrict__ Wv, unsigned short* __restrict__ Wt)
{
    __shared__ float tl[64][65];
    const int w = blockIdx.x >> 4, kt = blockIdx.x & 15;
    const float* W = (w == 0) ? Wk : (w == 1) ? Wq : Wv;
    const int tid = threadIdx.x;
#pragma unroll
    for (int rep = 0; rep < 4; rep++) {
        int flat = rep * 256 + tid;
        int rr = flat >> 4, c4 = (flat & 15) * 4;
        f32x4 v = *(const f32x4*)(W + (kt * 64 + rr) * 64 + c4);
#pragma unroll
        for (int jj = 0; jj < 4; jj++) tl[c4 + jj][rr] = v[jj];
    }
    __syncthreads();
#pragma unroll
    for (int rep = 0; rep < 2; rep++) {
        int flat = rep * 256 + tid;
        int n = flat >> 3, k8 = (flat & 7) * 8;
        u16x8 h;
#pragma unroll
        for (int jj = 0; jj < 8; jj++) h[jj] = f2bf(tl[n][k8 + jj]);
        *(u16x8*)(Wt + w * 65536 + n * 1024 + kt * 64 + k8) = h;
    }
}

// ---------------- Kernel 1: QKV v4 — M=64/block, W amortized 2x ----------------
// 256 blocks x 256 thr, 4 waves = 2 m-groups(32 rows, 2 A-frags) x 2 n-groups(6 nt).
// Per wave-iter: 16 LDS reads feed 24 MFMA (was 14 reads / 12 MFMA) -> 1.8x less
// LDS traffic per output. Single-barrier register-prefetch pipeline as v3.
__global__ __launch_bounds__(256) void qkv_k(
    const float* __restrict__ x, const unsigned short* __restrict__ Wt,
    unsigned short* __restrict__ Qb, unsigned short* __restrict__ Kb,
    unsigned short* __restrict__ Vt)
{
    __shared__ __align__(16) unsigned short xl[2][64][72];   // +8 pad
    __shared__ __align__(16) unsigned short wl[2][192][72];
    const int tid = threadIdx.x;
    const int wid = tid >> 6, lane = tid & 63;
    const int lrow = lane & 15, g = lane >> 4;
    const int mbase = blockIdx.x * 64;
    const int msrow = (wid & 1) * 32;        // 2 m-groups of 32 rows
    const int ntbase = (wid >> 1) * 6;       // 2 n-groups of 6 tiles

    const int xrow = tid >> 2, xc16 = (tid & 3) * 16;   // x: 16 f32/thread (64 rows)
    const int wrow = tid >> 3, wc8 = (tid & 7) * 8;     // W: 6 rows, 32 apart

    f32x4 acc0[6], acc1[6];
#pragma unroll
    for (int j = 0; j < 6; j++) {
        acc0[j] = (f32x4){0.f, 0.f, 0.f, 0.f};
        acc1[j] = (f32x4){0.f, 0.f, 0.f, 0.f};
    }

    // prologue: chunk 0 into regs
    f32x4 vx0, vx1, vx2, vx3;
    u16x8 rw0, rw1, rw2, rw3, rw4, rw5;
    {
        const float* xs = x + (mbase + xrow) * 1024 + xc16;
        vx0 = *(const f32x4*)(xs);      vx1 = *(const f32x4*)(xs + 4);
        vx2 = *(const f32x4*)(xs + 8);  vx3 = *(const f32x4*)(xs + 12);
        const unsigned short* ws = Wt + wrow * 1024 + wc8;
        rw0 = *(const u16x8*)(ws);
        rw1 = *(const u16x8*)(ws + 32 * 1024);
        rw2 = *(const u16x8*)(ws + 64 * 1024);
        rw3 = *(const u16x8*)(ws + 96 * 1024);
        rw4 = *(const u16x8*)(ws + 128 * 1024);
        rw5 = *(const u16x8*)(ws + 160 * 1024);
    }

#pragma unroll 1
    for (int t = 0; t < 16; ++t) {
        const int buf = t & 1;
        {
            unsigned d0, d1, d2, d3, d4, d5, d6, d7;
            asm("v_cvt_pk_bf16_f32 %0, %1, %2" : "=v"(d0) : "v"(vx0[0]), "v"(vx0[1]));
            asm("v_cvt_pk_bf16_f32 %0, %1, %2" : "=v"(d1) : "v"(vx0[2]), "v"(vx0[3]));
            asm("v_cvt_pk_bf16_f32 %0, %1, %2" : "=v"(d2) : "v"(vx1[0]), "v"(vx1[1]));
            asm("v_cvt_pk_bf16_f32 %0, %1, %2" : "=v"(d3) : "v"(vx1[2]), "v"(vx1[3]));
            asm("v_cvt_pk_bf16_f32 %0, %1, %2" : "=v"(d4) : "v"(vx2[0]), "v"(vx2[1]));
            asm("v_cvt_pk_bf16_f32 %0, %1, %2" : "=v"(d5) : "v"(vx2[2]), "v"(vx2[3]));
            asm("v_cvt_pk_bf16_f32 %0, %1, %2" : "=v"(d6) : "v"(vx3[0]), "v"(vx3[1]));
            asm("v_cvt_pk_bf16_f32 %0, %1, %2" : "=v"(d7) : "v"(vx3[2]), "v"(vx3[3]));
            u32x4 pk0; pk0[0] = d0; pk0[1] = d1; pk0[2] = d2; pk0[3] = d3;
            u32x4 pk1; pk1[0] = d4; pk1[1] = d5; pk1[2] = d6; pk1[3] = d7;
            *(u32x4*)&xl[buf][xrow][xc16]     = pk0;
            *(u32x4*)&xl[buf][xrow][xc16 + 8] = pk1;
            *(u16x8*)&wl[buf][wrow][wc8]        = rw0;
            *(u16x8*)&wl[buf][wrow + 32][wc8]   = rw1;
            *(u16x8*)&wl[buf][wrow + 64][wc8]   = rw2;
            *(u16x8*)&wl[buf][wrow + 96][wc8]   = rw3;
            *(u16x8*)&wl[buf][wrow + 128][wc8]  = rw4;
            *(u16x8*)&wl[buf][wrow + 160][wc8]  = rw5;
        }
        if (t < 15) {                        // next chunk's loads, in flight across barrier
            const int kc = (t + 1) * 64;
            const float* xs = x + (mbase + xrow) * 1024 + kc + xc16;
            vx0 = *(const f32x4*)(xs);      vx1 = *(const f32x4*)(xs + 4);
            vx2 = *(const f32x4*)(xs + 8);  vx3 = *(const f32x4*)(xs + 12);
            const unsigned short* ws = Wt + wrow * 1024 + kc + wc8;
            rw0 = *(const u16x8*)(ws);
            rw1 = *(const u16x8*)(ws + 32 * 1024);
            rw2 = *(const u16x8*)(ws + 64 * 1024);
            rw3 = *(const u16x8*)(ws + 96 * 1024);
            rw4 = *(const u16x8*)(ws + 128 * 1024);
            rw5 = *(const u16x8*)(ws + 160 * 1024);
        }
        __syncthreads();
#pragma unroll
        for (int ks = 0; ks < 2; ks++) {
            bf16x8 a0 = *(const bf16x8*)&xl[buf][msrow + lrow][ks * 32 + g * 8];
            bf16x8 a1 = *(const bf16x8*)&xl[buf][msrow + 16 + lrow][ks * 32 + g * 8];
#pragma unroll
            for (int j = 0; j < 6; j++) {
                bf16x8 b = *(const bf16x8*)&wl[buf][(ntbase + j) * 16 + lrow][ks * 32 + g * 8];
                acc0[j] = MFMA(a0, b, acc0[j]);
                acc1[j] = MFMA(a1, b, acc1[j]);
            }
        }
    }

#pragma unroll
    for (int j = 0; j < 6; j++) {
        int nt = ntbase + j;
        int w = nt >> 2;
        int col = (nt & 3) * 16 + lrow;
#pragma unroll
        for (int ms = 0; ms < 2; ms++) {
            const f32x4& a = ms ? acc1[j] : acc0[j];
            int r0 = mbase + msrow + ms * 16 + g * 4;
            if (w == 2) {
                int b = r0 >> 11, tt = r0 & 2047;
                u16x4 pv;
                pv[0] = f2bf(a[0]); pv[1] = f2bf(a[1]);
                pv[2] = f2bf(a[2]); pv[3] = f2bf(a[3]);
                *(u16x4*)(Vt + b * 131072 + col * 2048 + tt) = pv;
            } else {
                unsigned short* dst = (w == 0) ? Kb : Qb;
#pragma unroll
                for (int i = 0; i < 4; i++)
                    dst[(r0 + i) * 64 + col] = f2bf(a[i]);
            }
        }
    }
}

// ---------------- Kernel 2: attention v12 (unchanged, verified round 12/13) ----------------
__global__ __launch_bounds__(256) void attn_k(
    const unsigned short* __restrict__ Qb, const unsigned short* __restrict__ Kb,
    const unsigned short* __restrict__ Vt, float* __restrict__ pO,
    float* __restrict__ pL)
{
    __shared__ __align__(16) unsigned short klds[2][64][64];
    __shared__ __align__(16) unsigned short vlds[2][64][64];
    const int tid = threadIdx.x;
    const int w = tid >> 6, lane = tid & 63;
    const int lrow = lane & 15, g = lane >> 4;
    const int bid = blockIdx.x;
    const int bandIdx = bid >> 5;
    const int batch = (bid >> 2) & 7;
    const int j = bid & 3;
    const int B = (bandIdx < 16) ? (31 - bandIdx) : (bandIdx - 16);

    const int qb  = B * 64;
    const int nch = B + 1;
    const int nc  = (nch > j) ? ((nch - j + 3) >> 2) : 0;

    const unsigned short* Kbase = Kb + batch * 2048 * 64;
    const unsigned short* Vbase = Vt + batch * 131072;
    const float C2 = 0.03125f * 1.44269504088896f;      // E^-0.5 * log2(e)

    const int sr = tid >> 2;
    const int sc32 = tid & 3;
    const int sb0 = sr * 128 + (((sc32 * 2)     ^ (sr & 7)) << 4);
    const int sb1 = sr * 128 + (((sc32 * 2 + 1) ^ (sr & 7)) << 4);

    const int swz = (lrow & 7) << 4;
    const int rb0 = (lrow) * 128, rb1 = (16 + lrow) * 128,
              rb2 = (32 + lrow) * 128, rb3 = (48 + lrow) * 128;
    const int gk0 = (g << 4) ^ swz;
    const int gk1 = ((4 + g) << 4) ^ swz;
    const bool odd = (g & 1);

    const unsigned short* Qrow = Qb + (batch * 2048 + qb + w * 16 + lrow) * 64;
    bf16x8 q0 = *(const bf16x8*)(Qrow + g * 8);
    bf16x8 q1 = *(const bf16x8*)(Qrow + 32 + g * 8);
    const int qglob = qb + w * 16 + lrow;

    f32x4 o0 = {0.f,0.f,0.f,0.f}, o1 = o0, o2 = o0, o3 = o0;
    float lsum = 0.f;

    u16x8 rk0 = {}, rk1 = {}, rv0 = {}, rv1 = {};
    if (nc > 0) {
        const int kvb = j * 64;
        const unsigned short* ksrc = Kbase + (kvb + sr) * 64 + sc32 * 16;
        rk0 = *(const u16x8*)(ksrc); rk1 = *(const u16x8*)(ksrc + 8);
        const unsigned short* vsrc = Vbase + sr * 2048 + kvb + sc32 * 16;
        rv0 = *(const u16x8*)(vsrc); rv1 = *(const u16x8*)(vsrc + 8);
        char* kb = (char*)&klds[0][0][0];
        char* vb = (char*)&vlds[0][0][0];
        *(u16x8*)(kb + sb0) = rk0; *(u16x8*)(kb + sb1) = rk1;
        *(u16x8*)(vb + sb0) = rv0; *(u16x8*)(vb + sb1) = rv1;
    }
    __syncthreads();

    for (int idx = 0; idx < nc; ++idx) {
        const int c = j + idx * 4;
        const int cur = idx & 1;
        const int kvbase = c * 64;
        if (idx + 1 < nc) {
            const int kvb = kvbase + 256;
            const unsigned short* ksrc = Kbase + (kvb + sr) * 64 + sc32 * 16;
            rk0 = *(const u16x8*)(ksrc); rk1 = *(const u16x8*)(ksrc + 8);
            const unsigned short* vsrc = Vbase + sr * 2048 + kvb + sc32 * 16;
            rv0 = *(const u16x8*)(vsrc); rv1 = *(const u16x8*)(vsrc + 8);
        }

        const char* kb = (const char*)&klds[cur][0][0];
        const char* vb = (const char*)&vlds[cur][0][0];

        f32x4 t0 = {0.f,0.f,0.f,0.f}, t1 = t0, t2 = t0, t3 = t0;
        {
            bf16x8 a;
            a = *(const bf16x8*)(kb + rb0 + gk0); t0 = MFMA(a, q0, t0);
            a = *(const bf16x8*)(kb + rb0 + gk1); t0 = MFMA(a, q1, t0);
            a = *(const bf16x8*)(kb + rb1 + gk0); t1 = MFMA(a, q0, t1);
            a = *(const bf16x8*)(kb + rb1 + gk1); t1 = MFMA(a, q1, t1);
            a = *(const bf16x8*)(kb + rb2 + gk0); t2 = MFMA(a, q0, t2);
            a = *(const bf16x8*)(kb + rb2 + gk1); t2 = MFMA(a, q1, t2);
            a = *(const bf16x8*)(kb + rb3 + gk0); t3 = MFMA(a, q0, t3);
            a = *(const bf16x8*)(kb + rb3 + gk1); t3 = MFMA(a, q1, t3);
        }

        const bool maskc = (c == nch - 1);
        float eA[4], eB[4], eC[4], eD[4];
#pragma unroll
        for (int u = 0; u < 4; u++) {
            float v0 = t0[u] * C2, v1 = t1[u] * C2,
                  v2 = t2[u] * C2, v3 = t3[u] * C2;
            if (maskc) {
                int kvr = kvbase + g * 4 + u;
                v0 = (kvr      > qglob) ? -INFINITY : v0;
                v1 = (kvr + 16 > qglob) ? -INFINITY : v1;
                v2 = (kvr + 32 > qglob) ? -INFINITY : v2;
                v3 = (kvr + 48 > qglob) ? -INFINITY : v3;
            }
            eA[u] = __builtin_exp2f(v0);
            eB[u] = __builtin_exp2f(v1);
            eC[u] = __builtin_exp2f(v2);
            eD[u] = __builtin_exp2f(v3);
            lsum += (eA[u] + eB[u]) + (eC[u] + eD[u]);
        }

        bf16x8 pa0 = pack_pa(eA[0],eA[1],eA[2],eA[3], eB[0],eB[1],eB[2],eB[3], odd);
        bf16x8 pa1 = pack_pa(eC[0],eC[1],eC[2],eC[3], eD[0],eD[1],eD[2],eD[3], odd);

        {
            bf16x8 vv;
            vv = *(const bf16x8*)(vb + rb0 + gk0); o0 = MFMA(pa0, vv, o0);
            vv = *(const bf16x8*)(vb + rb0 + gk1); o0 = MFMA(pa1, vv, o0);
            vv = *(const bf16x8*)(vb + rb1 + gk0); o1 = MFMA(pa0, vv, o1);
            vv = *(const bf16x8*)(vb + rb1 + gk1); o1 = MFMA(pa1, vv, o1);
            vv = *(const bf16x8*)(vb + rb2 + gk0); o2 = MFMA(pa0, vv, o2);
            vv = *(const bf16x8*)(vb + rb2 + gk1); o2 = MFMA(pa1, vv, o2);
            vv = *(const bf16x8*)(vb + rb3 + gk0); o3 = MFMA(pa0, vv, o3);
            vv = *(const bf16x8*)(vb + rb3 + gk1); o3 = MFMA(pa1, vv, o3);
        }

        __syncthreads();
        if (idx + 1 < nc) {
            char* kw = (char*)&klds[cur ^ 1][0][0];
            char* vw = (char*)&vlds[cur ^ 1][0][0];
            *(u16x8*)(kw + sb0) = rk0; *(u16x8*)(kw + sb1) = rk1;
            *(u16x8*)(vw + sb0) = rv0; *(u16x8*)(vw + sb1) = rv1;
        }
        __syncthreads();
    }

    const int qrow0 = batch * 2048 + qb + w * 16;
    float* po = pO + ((size_t)j * 16384 + qrow0) * 64;
#pragma unroll
    for (int u = 0; u < 4; u++) {
        int r = (g * 4 + u) * 64;
        po[r +      lrow] = o0[u];
        po[r + 16 + lrow] = o1[u];
        po[r + 32 + lrow] = o2[u];
        po[r + 48 + lrow] = o3[u];
    }
    lsum += __shfl_xor(lsum, 16);
    lsum += __shfl_xor(lsum, 32);
    if (lane < 16) pL[j * 16384 + qrow0 + lane] = lsum;
}

// ---------------- Kernel 3: merge the four kv-quarter partials ----------------
__global__ __launch_bounds__(256) void comb_k(
    const float* __restrict__ pO, const float* __restrict__ pL,
    float* __restrict__ out)
{
    const int J = 16384 * 64;
    int id = blockIdx.x * 256 + threadIdx.x;
    int row = id >> 2, q = (id & 3) * 16;
    float inv = 1.f / (pL[row] + pL[16384 + row] + pL[32768 + row] + pL[49152 + row]);
    const float* p0 = pO + row * 64 + q;
    float* op = out + row * 64 + q;
#pragma unroll
    for (int k = 0; k < 4; k++) {
        f32x4 s = *(const f32x4*)(p0 + 4 * k)
                + *(const f32x4*)(p0 + J + 4 * k)
                + *(const f32x4*)(p0 + 2 * J + 4 * k)
                + *(const f32x4*)(p0 + 3 * J + 4 * k);
        *(f32x4*)(op + 4 * k) = s * inv;
    }
}

extern "C" void kernel_launch(void* const* d_in, const int* in_sizes, int n_in,
                              void* d_out, int out_size, void* d_ws, size_t ws_size,
                              hipStream_t stream) {
    const float* x  = (const float*)d_in[0];
    const float* Wk = (const float*)d_in[1];
    const float* Wq = (const float*)d_in[2];
    const float* Wv = (const float*)d_in[3];
    float* out = (float*)d_out;

    unsigned short* Wt = (unsigned short*)d_ws;        // [192][1024] bf16
    unsigned short* Kb = Wt + 3 * 65536;               // [16384][64]
    unsigned short* Qb = Kb + 16384 * 64;              // [16384][64]
    unsigned short* Vt = Qb + 16384 * 64;              // [8][64][2048]
    float* pO = (float*)(Vt + 131072 * 8);             // [4][16384][64] f32 partial o
    float* pL = pO + 4 * 16384 * 64;                   // [4][16384] f32 partial l

    wtrans_k<<<48, 256, 0, stream>>>(Wk, Wq, Wv, Wt);
    qkv_k<<<256, 256, 0, stream>>>(x, Wt, Qb, Kb, Vt);
    attn_k<<<1024, 256, 0, stream>>>(Qb, Kb, Vt, pO, pL);
    comb_k<<<256, 256, 0, stream>>>(pO, pL, out);
}

// Round 15
// 46.467 us; speedup vs baseline: 2.0524x; 1.0171x over previous
//
#include <hip/hip_runtime.h>

typedef __attribute__((ext_vector_type(8))) short bf16x8;
typedef __attribute__((ext_vector_type(4))) float f32x4;
typedef __attribute__((ext_vector_type(4))) unsigned short u16x4;
typedef __attribute__((ext_vector_type(8))) unsigned short u16x8;
typedef __attribute__((ext_vector_type(4))) unsigned int u32x4;

#define MFMA(a, b, c) __builtin_amdgcn_mfma_f32_16x16x32_bf16(a, b, c, 0, 0, 0)

static __device__ __forceinline__ unsigned short f2bf(float x) {
    union { float f; unsigned u; } v; v.f = x;
    unsigned r = v.u + 0x7fffu + ((v.u >> 16) & 1u);   // round-to-nearest-even
    return (unsigned short)(r >> 16);
}

// P-fragment pack (verified rounds 4-14).
static __device__ __forceinline__ bf16x8 pack_pa(
    float ea0, float ea1, float ea2, float ea3,
    float eb0, float eb1, float eb2, float eb3, bool odd)
{
    unsigned a1, a2, b1, b2;
    asm("v_cvt_pk_bf16_f32 %0, %1, %2" : "=v"(a1) : "v"(ea0), "v"(ea1));
    asm("v_cvt_pk_bf16_f32 %0, %1, %2" : "=v"(a2) : "v"(ea2), "v"(ea3));
    asm("v_cvt_pk_bf16_f32 %0, %1, %2" : "=v"(b1) : "v"(eb0), "v"(eb1));
    asm("v_cvt_pk_bf16_f32 %0, %1, %2" : "=v"(b2) : "v"(eb2), "v"(eb3));
    asm("v_permlane32_swap_b32 %0, %1" : "+v"(a1), "+v"(b1));
    asm("v_permlane32_swap_b32 %0, %1" : "+v"(a2), "+v"(b2));
    int sa1 = __shfl_xor((int)a1, 16);
    int sa2 = __shfl_xor((int)a2, 16);
    int sb1 = __shfl_xor((int)b1, 16);
    int sb2 = __shfl_xor((int)b2, 16);
    u32x4 paw;
    paw[0] = odd ? (unsigned)sb1 : a1;
    paw[1] = odd ? (unsigned)sb2 : a2;
    paw[2] = odd ? b1 : (unsigned)sa1;
    paw[3] = odd ? b2 : (unsigned)sa2;
    return __builtin_bit_cast(bf16x8, paw);
}

// ---------------- Kernel 0: W [1024][64] f32 -> Wt2 [16 kt][192 n][64] bf16 ----------------
// k-chunked so each chunk's W is a contiguous 24KB block; 16B granules XOR-swizzled by n&7
// so qkv's LINEAR LDS copy yields conflict-free b128 fragment reads.
__global__ __launch_bounds__(256) void wtrans_k(
    const float* __restrict__ Wk, const float* __restrict__ Wq,
    const float* __restrict__ Wv, unsigned short* __restrict__ Wt)
{
    __shared__ float tl[64][65];
    const int w = blockIdx.x >> 4, kt = blockIdx.x & 15;
    const float* W = (w == 0) ? Wk : (w == 1) ? Wq : Wv;
    const int tid = threadIdx.x;
#pragma unroll
    for (int rep = 0; rep < 4; rep++) {
        int flat = rep * 256 + tid;
        int rr = flat >> 4, c4 = (flat & 15) * 4;
        f32x4 v = *(const f32x4*)(W + (kt * 64 + rr) * 64 + c4);
#pragma unroll
        for (int jj = 0; jj < 4; jj++) tl[c4 + jj][rr] = v[jj];
    }
    __syncthreads();
#pragma unroll
    for (int rep = 0; rep < 2; rep++) {
        int flat = rep * 256 + tid;
        int n = flat >> 3, k8 = (flat & 7) * 8;      // n local 0..63, k8 local 0..56
        u16x8 h;
#pragma unroll
        for (int jj = 0; jj < 8; jj++) h[jj] = f2bf(tl[n][k8 + jj]);
        int grow = w * 64 + n;                        // global n-row 0..191
        int gr = (k8 >> 3) ^ (grow & 7);              // swizzled 16B-granule slot
        *(u16x8*)(Wt + kt * 12288 + grow * 64 + gr * 8) = h;
    }
}

// ---------------- Kernel 1: QKV v5 — contiguous 1KB wave streams ----------------
// 256 blocks x 256 thr, M=64, 4 waves = 2m x 2n. Staging loads are per-instruction
// CONTIGUOUS (lane i -> base + i*16B): W = 6x1KB/wave from k-chunked Wt2 (swizzled),
// x = 256B full row-segments. Single-barrier register-prefetch pipeline as v4.
__global__ __launch_bounds__(256) void qkv_k(
    const float* __restrict__ x, const unsigned short* __restrict__ Wt,
    unsigned short* __restrict__ Qb, unsigned short* __restrict__ Kb,
    unsigned short* __restrict__ Vt)
{
    __shared__ __align__(16) unsigned short xl[2][64][72];   // +8 pad
    __shared__ __align__(16) unsigned short wl[2][12288];    // linear [192][64], swizzled
    const int tid = threadIdx.x;
    const int wid = tid >> 6, lane = tid & 63;
    const int lrow = lane & 15, g = lane >> 4;
    const int mbase = blockIdx.x * 64;
    const int msrow = (wid & 1) * 32;        // 2 m-groups of 32 rows
    const int ntbase = (wid >> 1) * 6;       // 2 n-groups of 6 tiles

    const int xr0 = tid >> 4;                // x row (round r adds 16)
    const int xc16 = (tid & 15) * 4;         // x float col (16B per lane)
    const int wofs = tid * 8;                // W elems within a 2048-elem stripe

    const int swz0 = ((g    ) ^ (lrow & 7)) << 3;   // B-frag granule, ks=0
    const int swz1 = ((g + 4) ^ (lrow & 7)) << 3;   // ks=1

    f32x4 acc0[6], acc1[6];
#pragma unroll
    for (int j = 0; j < 6; j++) {
        acc0[j] = (f32x4){0.f, 0.f, 0.f, 0.f};
        acc1[j] = (f32x4){0.f, 0.f, 0.f, 0.f};
    }

    // prologue: chunk 0 into regs
    f32x4 vx0, vx1, vx2, vx3;
    u16x8 rw0, rw1, rw2, rw3, rw4, rw5;
    {
        const float* xs = x + mbase * 1024 + xc16;
        vx0 = *(const f32x4*)(xs + (xr0     ) * 1024);
        vx1 = *(const f32x4*)(xs + (xr0 + 16) * 1024);
        vx2 = *(const f32x4*)(xs + (xr0 + 32) * 1024);
        vx3 = *(const f32x4*)(xs + (xr0 + 48) * 1024);
        const unsigned short* ws = Wt + wofs;
        rw0 = *(const u16x8*)(ws);
        rw1 = *(const u16x8*)(ws + 2048);
        rw2 = *(const u16x8*)(ws + 4096);
        rw3 = *(const u16x8*)(ws + 6144);
        rw4 = *(const u16x8*)(ws + 8192);
        rw5 = *(const u16x8*)(ws + 10240);
    }

#pragma unroll 1
    for (int t = 0; t < 16; ++t) {
        const int buf = t & 1;
        // write staged regs -> LDS (x converted to bf16 here)
        {
            unsigned d0, d1;
            unsigned* p;
            asm("v_cvt_pk_bf16_f32 %0, %1, %2" : "=v"(d0) : "v"(vx0[0]), "v"(vx0[1]));
            asm("v_cvt_pk_bf16_f32 %0, %1, %2" : "=v"(d1) : "v"(vx0[2]), "v"(vx0[3]));
            p = (unsigned*)&xl[buf][xr0][xc16];      p[0] = d0; p[1] = d1;
            asm("v_cvt_pk_bf16_f32 %0, %1, %2" : "=v"(d0) : "v"(vx1[0]), "v"(vx1[1]));
            asm("v_cvt_pk_bf16_f32 %0, %1, %2" : "=v"(d1) : "v"(vx1[2]), "v"(vx1[3]));
            p = (unsigned*)&xl[buf][xr0 + 16][xc16]; p[0] = d0; p[1] = d1;
            asm("v_cvt_pk_bf16_f32 %0, %1, %2" : "=v"(d0) : "v"(vx2[0]), "v"(vx2[1]));
            asm("v_cvt_pk_bf16_f32 %0, %1, %2" : "=v"(d1) : "v"(vx2[2]), "v"(vx2[3]));
            p = (unsigned*)&xl[buf][xr0 + 32][xc16]; p[0] = d0; p[1] = d1;
            asm("v_cvt_pk_bf16_f32 %0, %1, %2" : "=v"(d0) : "v"(vx3[0]), "v"(vx3[1]));
            asm("v_cvt_pk_bf16_f32 %0, %1, %2" : "=v"(d1) : "v"(vx3[2]), "v"(vx3[3]));
            p = (unsigned*)&xl[buf][xr0 + 48][xc16]; p[0] = d0; p[1] = d1;

            *(u16x8*)&wl[buf][wofs        ] = rw0;
            *(u16x8*)&wl[buf][wofs + 2048 ] = rw1;
            *(u16x8*)&wl[buf][wofs + 4096 ] = rw2;
            *(u16x8*)&wl[buf][wofs + 6144 ] = rw3;
            *(u16x8*)&wl[buf][wofs + 8192 ] = rw4;
            *(u16x8*)&wl[buf][wofs + 10240] = rw5;
        }
        // issue next chunk's loads (in flight across the barrier)
        if (t < 15) {
            const int kc = (t + 1) * 64;
            const float* xs = x + mbase * 1024 + kc + xc16;
            vx0 = *(const f32x4*)(xs + (xr0     ) * 1024);
            vx1 = *(const f32x4*)(xs + (xr0 + 16) * 1024);
            vx2 = *(const f32x4*)(xs + (xr0 + 32) * 1024);
            vx3 = *(const f32x4*)(xs + (xr0 + 48) * 1024);
            const unsigned short* ws = Wt + (t + 1) * 12288 + wofs;
            rw0 = *(const u16x8*)(ws);
            rw1 = *(const u16x8*)(ws + 2048);
            rw2 = *(const u16x8*)(ws + 4096);
            rw3 = *(const u16x8*)(ws + 6144);
            rw4 = *(const u16x8*)(ws + 8192);
            rw5 = *(const u16x8*)(ws + 10240);
        }
        __syncthreads();
#pragma unroll
        for (int ks = 0; ks < 2; ks++) {
            bf16x8 a0 = *(const bf16x8*)&xl[buf][msrow + lrow][ks * 32 + g * 8];
            bf16x8 a1 = *(const bf16x8*)&xl[buf][msrow + 16 + lrow][ks * 32 + g * 8];
            const int swz = ks ? swz1 : swz0;
#pragma unroll
            for (int j = 0; j < 6; j++) {
                int row = (ntbase + j) * 16 + lrow;
                bf16x8 b = *(const bf16x8*)&wl[buf][row * 64 + swz];
                acc0[j] = MFMA(a0, b, acc0[j]);
                acc1[j] = MFMA(a1, b, acc1[j]);
            }
        }
    }

#pragma unroll
    for (int j = 0; j < 6; j++) {
        int nt = ntbase + j;
        int w = nt >> 2;
        int col = (nt & 3) * 16 + lrow;
#pragma unroll
        for (int ms = 0; ms < 2; ms++) {
            const f32x4& a = ms ? acc1[j] : acc0[j];
            int r0 = mbase + msrow + ms * 16 + g * 4;
            if (w == 2) {
                int b = r0 >> 11, tt = r0 & 2047;
                u16x4 pv;
                pv[0] = f2bf(a[0]); pv[1] = f2bf(a[1]);
                pv[2] = f2bf(a[2]); pv[3] = f2bf(a[3]);
                *(u16x4*)(Vt + b * 131072 + col * 2048 + tt) = pv;
            } else {
                unsigned short* dst = (w == 0) ? Kb : Qb;
#pragma unroll
                for (int i = 0; i < 4; i++)
                    dst[(r0 + i) * 64 + col] = f2bf(a[i]);
            }
        }
    }
}

// ---------------- Kernel 2: attention v12 (unchanged, verified rounds 12-14) ----------------
__global__ __launch_bounds__(256) void attn_k(
    const unsigned short* __restrict__ Qb, const unsigned short* __restrict__ Kb,
    const unsigned short* __restrict__ Vt, float* __restrict__ pO,
    float* __restrict__ pL)
{
    __shared__ __align__(16) unsigned short klds[2][64][64];
    __shared__ __align__(16) unsigned short vlds[2][64][64];
    const int tid = threadIdx.x;
    const int w = tid >> 6, lane = tid & 63;
    const int lrow = lane & 15, g = lane >> 4;
    const int bid = blockIdx.x;
    const int bandIdx = bid >> 5;
    const int batch = (bid >> 2) & 7;
    const int j = bid & 3;
    const int B = (bandIdx < 16) ? (31 - bandIdx) : (bandIdx - 16);

    const int qb  = B * 64;
    const int nch = B + 1;
    const int nc  = (nch > j) ? ((nch - j + 3) >> 2) : 0;

    const unsigned short* Kbase = Kb + batch * 2048 * 64;
    const unsigned short* Vbase = Vt + batch * 131072;
    const float C2 = 0.03125f * 1.44269504088896f;      // E^-0.5 * log2(e)

    const int sr = tid >> 2;
    const int sc32 = tid & 3;
    const int sb0 = sr * 128 + (((sc32 * 2)     ^ (sr & 7)) << 4);
    const int sb1 = sr * 128 + (((sc32 * 2 + 1) ^ (sr & 7)) << 4);

    const int swz = (lrow & 7) << 4;
    const int rb0 = (lrow) * 128, rb1 = (16 + lrow) * 128,
              rb2 = (32 + lrow) * 128, rb3 = (48 + lrow) * 128;
    const int gk0 = (g << 4) ^ swz;
    const int gk1 = ((4 + g) << 4) ^ swz;
    const bool odd = (g & 1);

    const unsigned short* Qrow = Qb + (batch * 2048 + qb + w * 16 + lrow) * 64;
    bf16x8 q0 = *(const bf16x8*)(Qrow + g * 8);
    bf16x8 q1 = *(const bf16x8*)(Qrow + 32 + g * 8);
    const int qglob = qb + w * 16 + lrow;

    f32x4 o0 = {0.f,0.f,0.f,0.f}, o1 = o0, o2 = o0, o3 = o0;
    float lsum = 0.f;

    u16x8 rk0 = {}, rk1 = {}, rv0 = {}, rv1 = {};
    if (nc > 0) {
        const int kvb = j * 64;
        const unsigned short* ksrc = Kbase + (kvb + sr) * 64 + sc32 * 16;
        rk0 = *(const u16x8*)(ksrc); rk1 = *(const u16x8*)(ksrc + 8);
        const unsigned short* vsrc = Vbase + sr * 2048 + kvb + sc32 * 16;
        rv0 = *(const u16x8*)(vsrc); rv1 = *(const u16x8*)(vsrc + 8);
        char* kb = (char*)&klds[0][0][0];
        char* vb = (char*)&vlds[0][0][0];
        *(u16x8*)(kb + sb0) = rk0; *(u16x8*)(kb + sb1) = rk1;
        *(u16x8*)(vb + sb0) = rv0; *(u16x8*)(vb + sb1) = rv1;
    }
    __syncthreads();

    for (int idx = 0; idx < nc; ++idx) {
        const int c = j + idx * 4;
        const int cur = idx & 1;
        const int kvbase = c * 64;
        if (idx + 1 < nc) {
            const int kvb = kvbase + 256;
            const unsigned short* ksrc = Kbase + (kvb + sr) * 64 + sc32 * 16;
            rk0 = *(const u16x8*)(ksrc); rk1 = *(const u16x8*)(ksrc + 8);
            const unsigned short* vsrc = Vbase + sr * 2048 + kvb + sc32 * 16;
            rv0 = *(const u16x8*)(vsrc); rv1 = *(const u16x8*)(vsrc + 8);
        }

        const char* kb = (const char*)&klds[cur][0][0];
        const char* vb = (const char*)&vlds[cur][0][0];

        f32x4 t0 = {0.f,0.f,0.f,0.f}, t1 = t0, t2 = t0, t3 = t0;
        {
            bf16x8 a;
            a = *(const bf16x8*)(kb + rb0 + gk0); t0 = MFMA(a, q0, t0);
            a = *(const bf16x8*)(kb + rb0 + gk1); t0 = MFMA(a, q1, t0);
            a = *(const bf16x8*)(kb + rb1 + gk0); t1 = MFMA(a, q0, t1);
            a = *(const bf16x8*)(kb + rb1 + gk1); t1 = MFMA(a, q1, t1);
            a = *(const bf16x8*)(kb + rb2 + gk0); t2 = MFMA(a, q0, t2);
            a = *(const bf16x8*)(kb + rb2 + gk1); t2 = MFMA(a, q1, t2);
            a = *(const bf16x8*)(kb + rb3 + gk0); t3 = MFMA(a, q0, t3);
            a = *(const bf16x8*)(kb + rb3 + gk1); t3 = MFMA(a, q1, t3);
        }

        const bool maskc = (c == nch - 1);
        float eA[4], eB[4], eC[4], eD[4];
#pragma unroll
        for (int u = 0; u < 4; u++) {
            float v0 = t0[u] * C2, v1 = t1[u] * C2,
                  v2 = t2[u] * C2, v3 = t3[u] * C2;
            if (maskc) {
                int kvr = kvbase + g * 4 + u;
                v0 = (kvr      > qglob) ? -INFINITY : v0;
                v1 = (kvr + 16 > qglob) ? -INFINITY : v1;
                v2 = (kvr + 32 > qglob) ? -INFINITY : v2;
                v3 = (kvr + 48 > qglob) ? -INFINITY : v3;
            }
            eA[u] = __builtin_exp2f(v0);
            eB[u] = __builtin_exp2f(v1);
            eC[u] = __builtin_exp2f(v2);
            eD[u] = __builtin_exp2f(v3);
            lsum += (eA[u] + eB[u]) + (eC[u] + eD[u]);
        }

        bf16x8 pa0 = pack_pa(eA[0],eA[1],eA[2],eA[3], eB[0],eB[1],eB[2],eB[3], odd);
        bf16x8 pa1 = pack_pa(eC[0],eC[1],eC[2],eC[3], eD[0],eD[1],eD[2],eD[3], odd);

        {
            bf16x8 vv;
            vv = *(const bf16x8*)(vb + rb0 + gk0); o0 = MFMA(pa0, vv, o0);
            vv = *(const bf16x8*)(vb + rb0 + gk1); o0 = MFMA(pa1, vv, o0);
            vv = *(const bf16x8*)(vb + rb1 + gk0); o1 = MFMA(pa0, vv, o1);
            vv = *(const bf16x8*)(vb + rb1 + gk1); o1 = MFMA(pa1, vv, o1);
            vv = *(const bf16x8*)(vb + rb2 + gk0); o2 = MFMA(pa0, vv, o2);
            vv = *(const bf16x8*)(vb + rb2 + gk1); o2 = MFMA(pa1, vv, o2);
            vv = *(const bf16x8*)(vb + rb3 + gk0); o3 = MFMA(pa0, vv, o3);
            vv = *(const bf16x8*)(vb + rb3 + gk1); o3 = MFMA(pa1, vv, o3);
        }

        __syncthreads();
        if (idx + 1 < nc) {
            char* kw = (char*)&klds[cur ^ 1][0][0];
            char* vw = (char*)&vlds[cur ^ 1][0][0];
            *(u16x8*)(kw + sb0) = rk0; *(u16x8*)(kw + sb1) = rk1;
            *(u16x8*)(vw + sb0) = rv0; *(u16x8*)(vw + sb1) = rv1;
        }
        __syncthreads();
    }

    const int qrow0 = batch * 2048 + qb + w * 16;
    float* po = pO + ((size_t)j * 16384 + qrow0) * 64;
#pragma unroll
    for (int u = 0; u < 4; u++) {
        int r = (g * 4 + u) * 64;
        po[r +      lrow] = o0[u];
        po[r + 16 + lrow] = o1[u];
        po[r + 32 + lrow] = o2[u];
        po[r + 48 + lrow] = o3[u];
    }
    lsum += __shfl_xor(lsum, 16);
    lsum += __shfl_xor(lsum, 32);
    if (lane < 16) pL[j * 16384 + qrow0 + lane] = lsum;
}

// ---------------- Kernel 3: merge the four kv-quarter partials ----------------
__global__ __launch_bounds__(256) void comb_k(
    const float* __restrict__ pO, const float* __restrict__ pL,
    float* __restrict__ out)
{
    const int J = 16384 * 64;
    int id = blockIdx.x * 256 + threadIdx.x;
    int row = id >> 2, q = (id & 3) * 16;
    float inv = 1.f / (pL[row] + pL[16384 + row] + pL[32768 + row] + pL[49152 + row]);
    const float* p0 = pO + row * 64 + q;
    float* op = out + row * 64 + q;
#pragma unroll
    for (int k = 0; k < 4; k++) {
        f32x4 s = *(const f32x4*)(p0 + 4 * k)
                + *(const f32x4*)(p0 + J + 4 * k)
                + *(const f32x4*)(p0 + 2 * J + 4 * k)
                + *(const f32x4*)(p0 + 3 * J + 4 * k);
        *(f32x4*)(op + 4 * k) = s * inv;
    }
}

extern "C" void kernel_launch(void* const* d_in, const int* in_sizes, int n_in,
                              void* d_out, int out_size, void* d_ws, size_t ws_size,
                              hipStream_t stream) {
    const float* x  = (const float*)d_in[0];
    const float* Wk = (const float*)d_in[1];
    const float* Wq = (const float*)d_in[2];
    const float* Wv = (const float*)d_in[3];
    float* out = (float*)d_out;

    unsigned short* Wt = (unsigned short*)d_ws;        // [16][192][64] bf16 (k-chunked, swizzled)
    unsigned short* Kb = Wt + 3 * 65536;               // [16384][64]
    unsigned short* Qb = Kb + 16384 * 64;              // [16384][64]
    unsigned short* Vt = Qb + 16384 * 64;              // [8][64][2048]
    float* pO = (float*)(Vt + 131072 * 8);             // [4][16384][64] f32 partial o
    float* pL = pO + 4 * 16384 * 64;                   // [4][16384] f32 partial l

    wtrans_k<<<48, 256, 0, stream>>>(Wk, Wq, Wv, Wt);
    qkv_k<<<256, 256, 0, stream>>>(x, Wt, Qb, Kb, Vt);
    attn_k<<<1024, 256, 0, stream>>>(Qb, Kb, Vt, pO, pL);
    comb_k<<<256, 256, 0, stream>>>(pO, pL, out);
}

// Round 16
// 46.231 us; speedup vs baseline: 2.0629x; 1.0051x over previous
//
#include <hip/hip_runtime.h>

typedef __attribute__((ext_vector_type(8))) short bf16x8;
typedef __attribute__((ext_vector_type(4))) float f32x4;
typedef __attribute__((ext_vector_type(4))) unsigned short u16x4;
typedef __attribute__((ext_vector_type(8))) unsigned short u16x8;
typedef __attribute__((ext_vector_type(4))) unsigned int u32x4;

#define MFMA(a, b, c) __builtin_amdgcn_mfma_f32_16x16x32_bf16(a, b, c, 0, 0, 0)

static __device__ __forceinline__ unsigned short f2bf(float x) {
    union { float f; unsigned u; } v; v.f = x;
    unsigned r = v.u + 0x7fffu + ((v.u >> 16) & 1u);   // round-to-nearest-even
    return (unsigned short)(r >> 16);
}

// P-fragment pack (verified rounds 4-14).
static __device__ __forceinline__ bf16x8 pack_pa(
    float ea0, float ea1, float ea2, float ea3,
    float eb0, float eb1, float eb2, float eb3, bool odd)
{
    unsigned a1, a2, b1, b2;
    asm("v_cvt_pk_bf16_f32 %0, %1, %2" : "=v"(a1) : "v"(ea0), "v"(ea1));
    asm("v_cvt_pk_bf16_f32 %0, %1, %2" : "=v"(a2) : "v"(ea2), "v"(ea3));
    asm("v_cvt_pk_bf16_f32 %0, %1, %2" : "=v"(b1) : "v"(eb0), "v"(eb1));
    asm("v_cvt_pk_bf16_f32 %0, %1, %2" : "=v"(b2) : "v"(eb2), "v"(eb3));
    asm("v_permlane32_swap_b32 %0, %1" : "+v"(a1), "+v"(b1));
    asm("v_permlane32_swap_b32 %0, %1" : "+v"(a2), "+v"(b2));
    int sa1 = __shfl_xor((int)a1, 16);
    int sa2 = __shfl_xor((int)a2, 16);
    int sb1 = __shfl_xor((int)b1, 16);
    int sb2 = __shfl_xor((int)b2, 16);
    u32x4 paw;
    paw[0] = odd ? (unsigned)sb1 : a1;
    paw[1] = odd ? (unsigned)sb2 : a2;
    paw[2] = odd ? b1 : (unsigned)sa1;
    paw[3] = odd ? b2 : (unsigned)sa2;
    return __builtin_bit_cast(bf16x8, paw);
}

// ---------------- Kernel 0: W [1024][64] f32 -> Wt2 [16 kt][192 n][64] bf16 ----------------
// k-chunked so each chunk's W is a contiguous 24KB block; 16B granules XOR-swizzled by n&7
// so qkv's LINEAR LDS copy yields conflict-free b128 fragment reads.
__global__ __launch_bounds__(256) void wtrans_k(
    const float* __restrict__ Wk, const float* __restrict__ Wq,
    const float* __restrict__ Wv, unsigned short* __restrict__ Wt)
{
    __shared__ float tl[64][65];
    const int w = blockIdx.x >> 4, kt = blockIdx.x & 15;
    const float* W = (w == 0) ? Wk : (w == 1) ? Wq : Wv;
    const int tid = threadIdx.x;
#pragma unroll
    for (int rep = 0; rep < 4; rep++) {
        int flat = rep * 256 + tid;
        int rr = flat >> 4, c4 = (flat & 15) * 4;
        f32x4 v = *(const f32x4*)(W + (kt * 64 + rr) * 64 + c4);
#pragma unroll
        for (int jj = 0; jj < 4; jj++) tl[c4 + jj][rr] = v[jj];
    }
    __syncthreads();
#pragma unroll
    for (int rep = 0; rep < 2; rep++) {
        int flat = rep * 256 + tid;
        int n = flat >> 3, k8 = (flat & 7) * 8;      // n local 0..63, k8 local 0..56
        u16x8 h;
#pragma unroll
        for (int jj = 0; jj < 8; jj++) h[jj] = f2bf(tl[n][k8 + jj]);
        int grow = w * 64 + n;                        // global n-row 0..191
        int gr = (k8 >> 3) ^ (grow & 7);              // swizzled 16B-granule slot
        *(u16x8*)(Wt + kt * 12288 + grow * 64 + gr * 8) = h;
    }
}

// ---------------- Kernel 1: QKV v5 — contiguous 1KB wave streams ----------------
// 256 blocks x 256 thr, M=64, 4 waves = 2m x 2n. Staging loads are per-instruction
// CONTIGUOUS (lane i -> base + i*16B): W = 6x1KB/wave from k-chunked Wt2 (swizzled),
// x = 256B full row-segments. Single-barrier register-prefetch pipeline as v4.
__global__ __launch_bounds__(256) void qkv_k(
    const float* __restrict__ x, const unsigned short* __restrict__ Wt,
    unsigned short* __restrict__ Qb, unsigned short* __restrict__ Kb,
    unsigned short* __restrict__ Vt)
{
    __shared__ __align__(16) unsigned short xl[2][64][72];   // +8 pad
    __shared__ __align__(16) unsigned short wl[2][12288];    // linear [192][64], swizzled
    const int tid = threadIdx.x;
    const int wid = tid >> 6, lane = tid & 63;
    const int lrow = lane & 15, g = lane >> 4;
    const int mbase = blockIdx.x * 64;
    const int msrow = (wid & 1) * 32;        // 2 m-groups of 32 rows
    const int ntbase = (wid >> 1) * 6;       // 2 n-groups of 6 tiles

    const int xr0 = tid >> 4;                // x row (round r adds 16)
    const int xc16 = (tid & 15) * 4;         // x float col (16B per lane)
    const int wofs = tid * 8;                // W elems within a 2048-elem stripe

    const int swz0 = ((g    ) ^ (lrow & 7)) << 3;   // B-frag granule, ks=0
    const int swz1 = ((g + 4) ^ (lrow & 7)) << 3;   // ks=1

    f32x4 acc0[6], acc1[6];
#pragma unroll
    for (int j = 0; j < 6; j++) {
        acc0[j] = (f32x4){0.f, 0.f, 0.f, 0.f};
        acc1[j] = (f32x4){0.f, 0.f, 0.f, 0.f};
    }

    // prologue: chunk 0 into regs
    f32x4 vx0, vx1, vx2, vx3;
    u16x8 rw0, rw1, rw2, rw3, rw4, rw5;
    {
        const float* xs = x + mbase * 1024 + xc16;
        vx0 = *(const f32x4*)(xs + (xr0     ) * 1024);
        vx1 = *(const f32x4*)(xs + (xr0 + 16) * 1024);
        vx2 = *(const f32x4*)(xs + (xr0 + 32) * 1024);
        vx3 = *(const f32x4*)(xs + (xr0 + 48) * 1024);
        const unsigned short* ws = Wt + wofs;
        rw0 = *(const u16x8*)(ws);
        rw1 = *(const u16x8*)(ws + 2048);
        rw2 = *(const u16x8*)(ws + 4096);
        rw3 = *(const u16x8*)(ws + 6144);
        rw4 = *(const u16x8*)(ws + 8192);
        rw5 = *(const u16x8*)(ws + 10240);
    }

#pragma unroll 1
    for (int t = 0; t < 16; ++t) {
        const int buf = t & 1;
        // write staged regs -> LDS (x converted to bf16 here)
        {
            unsigned d0, d1;
            unsigned* p;
            asm("v_cvt_pk_bf16_f32 %0, %1, %2" : "=v"(d0) : "v"(vx0[0]), "v"(vx0[1]));
            asm("v_cvt_pk_bf16_f32 %0, %1, %2" : "=v"(d1) : "v"(vx0[2]), "v"(vx0[3]));
            p = (unsigned*)&xl[buf][xr0][xc16];      p[0] = d0; p[1] = d1;
            asm("v_cvt_pk_bf16_f32 %0, %1, %2" : "=v"(d0) : "v"(vx1[0]), "v"(vx1[1]));
            asm("v_cvt_pk_bf16_f32 %0, %1, %2" : "=v"(d1) : "v"(vx1[2]), "v"(vx1[3]));
            p = (unsigned*)&xl[buf][xr0 + 16][xc16]; p[0] = d0; p[1] = d1;
            asm("v_cvt_pk_bf16_f32 %0, %1, %2" : "=v"(d0) : "v"(vx2[0]), "v"(vx2[1]));
            asm("v_cvt_pk_bf16_f32 %0, %1, %2" : "=v"(d1) : "v"(vx2[2]), "v"(vx2[3]));
            p = (unsigned*)&xl[buf][xr0 + 32][xc16]; p[0] = d0; p[1] = d1;
            asm("v_cvt_pk_bf16_f32 %0, %1, %2" : "=v"(d0) : "v"(vx3[0]), "v"(vx3[1]));
            asm("v_cvt_pk_bf16_f32 %0, %1, %2" : "=v"(d1) : "v"(vx3[2]), "v"(vx3[3]));
            p = (unsigned*)&xl[buf][xr0 + 48][xc16]; p[0] = d0; p[1] = d1;

            *(u16x8*)&wl[buf][wofs        ] = rw0;
            *(u16x8*)&wl[buf][wofs + 2048 ] = rw1;
            *(u16x8*)&wl[buf][wofs + 4096 ] = rw2;
            *(u16x8*)&wl[buf][wofs + 6144 ] = rw3;
            *(u16x8*)&wl[buf][wofs + 8192 ] = rw4;
            *(u16x8*)&wl[buf][wofs + 10240] = rw5;
        }
        // issue next chunk's loads (in flight across the barrier)
        if (t < 15) {
            const int kc = (t + 1) * 64;
            const float* xs = x + mbase * 1024 + kc + xc16;
            vx0 = *(const f32x4*)(xs + (xr0     ) * 1024);
            vx1 = *(const f32x4*)(xs + (xr0 + 16) * 1024);
            vx2 = *(const f32x4*)(xs + (xr0 + 32) * 1024);
            vx3 = *(const f32x4*)(xs + (xr0 + 48) * 1024);
            const unsigned short* ws = Wt + (t + 1) * 12288 + wofs;
            rw0 = *(const u16x8*)(ws);
            rw1 = *(const u16x8*)(ws + 2048);
            rw2 = *(const u16x8*)(ws + 4096);
            rw3 = *(const u16x8*)(ws + 6144);
            rw4 = *(const u16x8*)(ws + 8192);
            rw5 = *(const u16x8*)(ws + 10240);
        }
        __syncthreads();
#pragma unroll
        for (int ks = 0; ks < 2; ks++) {
            bf16x8 a0 = *(const bf16x8*)&xl[buf][msrow + lrow][ks * 32 + g * 8];
            bf16x8 a1 = *(const bf16x8*)&xl[buf][msrow + 16 + lrow][ks * 32 + g * 8];
            const int swz = ks ? swz1 : swz0;
#pragma unroll
            for (int j = 0; j < 6; j++) {
                int row = (ntbase + j) * 16 + lrow;
                bf16x8 b = *(const bf16x8*)&wl[buf][row * 64 + swz];
                acc0[j] = MFMA(a0, b, acc0[j]);
                acc1[j] = MFMA(a1, b, acc1[j]);
            }
        }
    }

#pragma unroll
    for (int j = 0; j < 6; j++) {
        int nt = ntbase + j;
        int w = nt >> 2;
        int col = (nt & 3) * 16 + lrow;
#pragma unroll
        for (int ms = 0; ms < 2; ms++) {
            const f32x4& a = ms ? acc1[j] : acc0[j];
            int r0 = mbase + msrow + ms * 16 + g * 4;
            if (w == 2) {
                int b = r0 >> 11, tt = r0 & 2047;
                u16x4 pv;
                pv[0] = f2bf(a[0]); pv[1] = f2bf(a[1]);
                pv[2] = f2bf(a[2]); pv[3] = f2bf(a[3]);
                *(u16x4*)(Vt + b * 131072 + col * 2048 + tt) = pv;
            } else {
                unsigned short* dst = (w == 0) ? Kb : Qb;
#pragma unroll
                for (int i = 0; i < 4; i++)
                    dst[(r0 + i) * 64 + col] = f2bf(a[i]);
            }
        }
    }
}

// ---------------- Kernel 2: attention v12 (unchanged, verified rounds 12-14) ----------------
__global__ __launch_bounds__(256) void attn_k(
    const unsigned short* __restrict__ Qb, const unsigned short* __restrict__ Kb,
    const unsigned short* __restrict__ Vt, float* __restrict__ pO,
    float* __restrict__ pL)
{
    __shared__ __align__(16) unsigned short klds[2][64][64];
    __shared__ __align__(16) unsigned short vlds[2][64][64];
    const int tid = threadIdx.x;
    const int w = tid >> 6, lane = tid & 63;
    const int lrow = lane & 15, g = lane >> 4;
    const int bid = blockIdx.x;
    const int bandIdx = bid >> 5;
    const int batch = (bid >> 2) & 7;
    const int j = bid & 3;
    const int B = (bandIdx < 16) ? (31 - bandIdx) : (bandIdx - 16);

    const int qb  = B * 64;
    const int nch = B + 1;
    const int nc  = (nch > j) ? ((nch - j + 3) >> 2) : 0;

    const unsigned short* Kbase = Kb + batch * 2048 * 64;
    const unsigned short* Vbase = Vt + batch * 131072;
    const float C2 = 0.03125f * 1.44269504088896f;      // E^-0.5 * log2(e)

    const int sr = tid >> 2;
    const int sc32 = tid & 3;
    const int sb0 = sr * 128 + (((sc32 * 2)     ^ (sr & 7)) << 4);
    const int sb1 = sr * 128 + (((sc32 * 2 + 1) ^ (sr & 7)) << 4);

    const int swz = (lrow & 7) << 4;
    const int rb0 = (lrow) * 128, rb1 = (16 + lrow) * 128,
              rb2 = (32 + lrow) * 128, rb3 = (48 + lrow) * 128;
    const int gk0 = (g << 4) ^ swz;
    const int gk1 = ((4 + g) << 4) ^ swz;
    const bool odd = (g & 1);

    const unsigned short* Qrow = Qb + (batch * 2048 + qb + w * 16 + lrow) * 64;
    bf16x8 q0 = *(const bf16x8*)(Qrow + g * 8);
    bf16x8 q1 = *(const bf16x8*)(Qrow + 32 + g * 8);
    const int qglob = qb + w * 16 + lrow;

    f32x4 o0 = {0.f,0.f,0.f,0.f}, o1 = o0, o2 = o0, o3 = o0;
    float lsum = 0.f;

    u16x8 rk0 = {}, rk1 = {}, rv0 = {}, rv1 = {};
    if (nc > 0) {
        const int kvb = j * 64;
        const unsigned short* ksrc = Kbase + (kvb + sr) * 64 + sc32 * 16;
        rk0 = *(const u16x8*)(ksrc); rk1 = *(const u16x8*)(ksrc + 8);
        const unsigned short* vsrc = Vbase + sr * 2048 + kvb + sc32 * 16;
        rv0 = *(const u16x8*)(vsrc); rv1 = *(const u16x8*)(vsrc + 8);
        char* kb = (char*)&klds[0][0][0];
        char* vb = (char*)&vlds[0][0][0];
        *(u16x8*)(kb + sb0) = rk0; *(u16x8*)(kb + sb1) = rk1;
        *(u16x8*)(vb + sb0) = rv0; *(u16x8*)(vb + sb1) = rv1;
    }
    __syncthreads();

    for (int idx = 0; idx < nc; ++idx) {
        const int c = j + idx * 4;
        const int cur = idx & 1;
        const int kvbase = c * 64;
        if (idx + 1 < nc) {
            const int kvb = kvbase + 256;
            const unsigned short* ksrc = Kbase + (kvb + sr) * 64 + sc32 * 16;
            rk0 = *(const u16x8*)(ksrc); rk1 = *(const u16x8*)(ksrc + 8);
            const unsigned short* vsrc = Vbase + sr * 2048 + kvb + sc32 * 16;
            rv0 = *(const u16x8*)(vsrc); rv1 = *(const u16x8*)(vsrc + 8);
        }

        const char* kb = (const char*)&klds[cur][0][0];
        const char* vb = (const char*)&vlds[cur][0][0];

        f32x4 t0 = {0.f,0.f,0.f,0.f}, t1 = t0, t2 = t0, t3 = t0;
        {
            bf16x8 a;
            a = *(const bf16x8*)(kb + rb0 + gk0); t0 = MFMA(a, q0, t0);
            a = *(const bf16x8*)(kb + rb0 + gk1); t0 = MFMA(a, q1, t0);
            a = *(const bf16x8*)(kb + rb1 + gk0); t1 = MFMA(a, q0, t1);
            a = *(const bf16x8*)(kb + rb1 + gk1); t1 = MFMA(a, q1, t1);
            a = *(const bf16x8*)(kb + rb2 + gk0); t2 = MFMA(a, q0, t2);
            a = *(const bf16x8*)(kb + rb2 + gk1); t2 = MFMA(a, q1, t2);
            a = *(const bf16x8*)(kb + rb3 + gk0); t3 = MFMA(a, q0, t3);
            a = *(const bf16x8*)(kb + rb3 + gk1); t3 = MFMA(a, q1, t3);
        }

        const bool maskc = (c == nch - 1);
        float eA[4], eB[4], eC[4], eD[4];
#pragma unroll
        for (int u = 0; u < 4; u++) {
            float v0 = t0[u] * C2, v1 = t1[u] * C2,
                  v2 = t2[u] * C2, v3 = t3[u] * C2;
            if (maskc) {
                int kvr = kvbase + g * 4 + u;
                v0 = (kvr      > qglob) ? -INFINITY : v0;
                v1 = (kvr + 16 > qglob) ? -INFINITY : v1;
                v2 = (kvr + 32 > qglob) ? -INFINITY : v2;
                v3 = (kvr + 48 > qglob) ? -INFINITY : v3;
            }
            eA[u] = __builtin_exp2f(v0);
            eB[u] = __builtin_exp2f(v1);
            eC[u] = __builtin_exp2f(v2);
            eD[u] = __builtin_exp2f(v3);
            lsum += (eA[u] + eB[u]) + (eC[u] + eD[u]);
        }

        bf16x8 pa0 = pack_pa(eA[0],eA[1],eA[2],eA[3], eB[0],eB[1],eB[2],eB[3], odd);
        bf16x8 pa1 = pack_pa(eC[0],eC[1],eC[2],eC[3], eD[0],eD[1],eD[2],eD[3], odd);

        {
            bf16x8 vv;
            vv = *(const bf16x8*)(vb + rb0 + gk0); o0 = MFMA(pa0, vv, o0);
            vv = *(const bf16x8*)(vb + rb0 + gk1); o0 = MFMA(pa1, vv, o0);
            vv = *(const bf16x8*)(vb + rb1 + gk0); o1 = MFMA(pa0, vv, o1);
            vv = *(const bf16x8*)(vb + rb1 + gk1); o1 = MFMA(pa1, vv, o1);
            vv = *(const bf16x8*)(vb + rb2 + gk0); o2 = MFMA(pa0, vv, o2);
            vv = *(const bf16x8*)(vb + rb2 + gk1); o2 = MFMA(pa1, vv, o2);
            vv = *(const bf16x8*)(vb + rb3 + gk0); o3 = MFMA(pa0, vv, o3);
            vv = *(const bf16x8*)(vb + rb3 + gk1); o3 = MFMA(pa1, vv, o3);
        }

        __syncthreads();
        if (idx + 1 < nc) {
            char* kw = (char*)&klds[cur ^ 1][0][0];
            char* vw = (char*)&vlds[cur ^ 1][0][0];
            *(u16x8*)(kw + sb0) = rk0; *(u16x8*)(kw + sb1) = rk1;
            *(u16x8*)(vw + sb0) = rv0; *(u16x8*)(vw + sb1) = rv1;
        }
        __syncthreads();
    }

    const int qrow0 = batch * 2048 + qb + w * 16;
    float* po = pO + ((size_t)j * 16384 + qrow0) * 64;
#pragma unroll
    for (int u = 0; u < 4; u++) {
        int r = (g * 4 + u) * 64;
        po[r +      lrow] = o0[u];
        po[r + 16 + lrow] = o1[u];
        po[r + 32 + lrow] = o2[u];
        po[r + 48 + lrow] = o3[u];
    }
    lsum += __shfl_xor(lsum, 16);
    lsum += __shfl_xor(lsum, 32);
    if (lane < 16) pL[j * 16384 + qrow0 + lane] = lsum;
}

// ---------------- Kernel 3: merge the four kv-quarter partials ----------------
__global__ __launch_bounds__(256) void comb_k(
    const float* __restrict__ pO, const float* __restrict__ pL,
    float* __restrict__ out)
{
    const int J = 16384 * 64;
    int id = blockIdx.x * 256 + threadIdx.x;
    int row = id >> 2, q = (id & 3) * 16;
    float inv = 1.f / (pL[row] + pL[16384 + row] + pL[32768 + row] + pL[49152 + row]);
    const float* p0 = pO + row * 64 + q;
    float* op = out + row * 64 + q;
#pragma unroll
    for (int k = 0; k < 4; k++) {
        f32x4 s = *(const f32x4*)(p0 + 4 * k)
                + *(const f32x4*)(p0 + J + 4 * k)
                + *(const f32x4*)(p0 + 2 * J + 4 * k)
                + *(const f32x4*)(p0 + 3 * J + 4 * k);
        *(f32x4*)(op + 4 * k) = s * inv;
    }
}

extern "C" void kernel_launch(void* const* d_in, const int* in_sizes, int n_in,
                              void* d_out, int out_size, void* d_ws, size_t ws_size,
                              hipStream_t stream) {
    const float* x  = (const float*)d_in[0];
    const float* Wk = (const float*)d_in[1];
    const float* Wq = (const float*)d_in[2];
    const float* Wv = (const float*)d_in[3];
    float* out = (float*)d_out;

    unsigned short* Wt = (unsigned short*)d_ws;        // [16][192][64] bf16 (k-chunked, swizzled)
    unsigned short* Kb = Wt + 3 * 65536;               // [16384][64]
    unsigned short* Qb = Kb + 16384 * 64;              // [16384][64]
    unsigned short* Vt = Qb + 16384 * 64;              // [8][64][2048]
    float* pO = (float*)(Vt + 131072 * 8);             // [4][16384][64] f32 partial o
    float* pL = pO + 4 * 16384 * 64;                   // [4][16384] f32 partial l

    wtrans_k<<<48, 256, 0, stream>>>(Wk, Wq, Wv, Wt);
    qkv_k<<<256, 256, 0, stream>>>(x, Wt, Qb, Kb, Vt);
    attn_k<<<1024, 256, 0, stream>>>(Qb, Kb, Vt, pO, pL);
    comb_k<<<256, 256, 0, stream>>>(pO, pL, out);
}